// Round 1
// baseline (317.367 us; speedup 1.0000x reference)
//
#include <hip/hip_runtime.h>

#define IMG   256
#define IMG2  65536
#define NB    64    // img batches
#define NB2   128   // heat/seg batches

// ---------------------------------------------------------------------------
// crops kernel: one block per (batch, cell). S = cell size, G = 256/S cells.
// For b >= 64 the cell is sourced from img at base max(ci*S-4, 0) (the Y-gather
// collapses to a shifted contiguous block). Normalize by cell min/max, gate by
// heat > 0.5.
// ---------------------------------------------------------------------------
template <int S>
__global__ void crops_kernel(const float* __restrict__ img,
                             const float* __restrict__ heat,
                             float* __restrict__ out) {
    constexpr int G    = IMG / S;
    constexpr int CELL = S * S;
    constexpr int NT   = (CELL < 256) ? CELL : 256;
    constexpr int PPT  = CELL / NT;

    const int b   = blockIdx.y;
    const int ci  = blockIdx.x / G;
    const int cj  = blockIdx.x - ci * G;
    const int tid = threadIdx.x;

    const int src = (b < NB) ? b : (b - NB);
    int bi = ci * S;
    int bj = cj * S;
    if (b >= NB) {
        if (ci != 0) bi -= 4;
        if (cj != 0) bj -= 4;
    }

    const float* sp = img + src * IMG2;

    float vals[PPT];
    float mn = 3.4e38f, mx = -3.4e38f;
#pragma unroll
    for (int k = 0; k < PPT; ++k) {
        const int p = tid + k * NT;
        const int r = p / S;
        const int c = p - r * S;
        const float v = sp[(bi + r) * IMG + (bj + c)];
        vals[k] = v;
        mn = fminf(mn, v);
        mx = fmaxf(mx, v);
    }

    // wave (64-lane) butterfly reduce
#pragma unroll
    for (int off = 1; off < 64; off <<= 1) {
        mn = fminf(mn, __shfl_xor(mn, off, 64));
        mx = fmaxf(mx, __shfl_xor(mx, off, 64));
    }

    if constexpr (NT > 64) {
        constexpr int NW = NT / 64;
        __shared__ float smn[NW];
        __shared__ float smx[NW];
        const int w = tid >> 6;
        if ((tid & 63) == 0) { smn[w] = mn; smx[w] = mx; }
        __syncthreads();
        mn = smn[0]; mx = smx[0];
#pragma unroll
        for (int w2 = 1; w2 < NW; ++w2) {
            mn = fminf(mn, smn[w2]);
            mx = fmaxf(mx, smx[w2]);
        }
    }

    const float m   = (heat[b * G * G + ci * G + cj] > 0.5f) ? 1.0f : 0.0f;
    const float inv = m / (mx - mn + 1e-5f);   // mask==0 -> exact 0 output

    float* dst = out + b * IMG2 + (ci * S) * IMG + (cj * S);
#pragma unroll
    for (int k = 0; k < PPT; ++k) {
        const int p = tid + k * NT;
        const int r = p / S;
        const int c = p - r * S;
        dst[r * IMG + c] = (vals[k] - mn) * inv;
    }
}

// ---------------------------------------------------------------------------
// label kernel: one thread per output pixel (b, u, v), b in [0,64).
// Direct part: mask(b, cell(u,v)) * seg[b].
// Scatter part inverted to a gather: preimage of u under Y is {u} if u<s,
// plus {u+4} if s-4 <= u <= 251.
// ---------------------------------------------------------------------------
__global__ void label_kernel(const float* __restrict__ heat8,
                             const float* __restrict__ heat16,
                             const float* __restrict__ heat32,
                             const float* __restrict__ seg8,
                             const float* __restrict__ seg16,
                             const float* __restrict__ seg32,
                             float* __restrict__ out) {
    const int b = blockIdx.y;
    const int p = blockIdx.x * blockDim.x + threadIdx.x;
    const int u = p >> 8;
    const int v = p & 255;

    float num = 0.0f, den = 0.0f;

    auto accum = [&](const float* __restrict__ heat,
                     const float* __restrict__ seg,
                     int g, int slog) {
        const int s = 1 << slog;
        // direct contribution
        if (heat[b * g * g + (u >> slog) * g + (v >> slog)] > 0.5f) {
            num += seg[b * IMG2 + p];
            den += 1.0f;
        }
        // inverted scatter contribution
        int iu[2]; int ni = 0;
        if (u < s)                 iu[ni++] = u;
        if (u >= s - 4 && u <= 251) iu[ni++] = u + 4;
        int jv[2]; int nj = 0;
        if (v < s)                 jv[nj++] = v;
        if (v >= s - 4 && v <= 251) jv[nj++] = v + 4;

        const float* h2 = heat + (NB + b) * g * g;
        const float* s2 = seg  + (NB + b) * IMG2;
        for (int a = 0; a < ni; ++a) {
            const int i  = iu[a];
            const int hr = (i >> slog) * g;
            for (int c = 0; c < nj; ++c) {
                const int j = jv[c];
                if (h2[hr + (j >> slog)] > 0.5f) {
                    num += s2[i * IMG + j];
                    den += 1.0f;
                }
            }
        }
    };

    accum(heat32, seg32, 32, 3);   // g=32, s=8
    accum(heat16, seg16, 16, 4);   // g=16, s=16
    accum(heat8,  seg8,  8,  5);   // g=8,  s=32

    out[b * IMG2 + p] = num / (den + 1e-10f);
}

extern "C" void kernel_launch(void* const* d_in, const int* in_sizes, int n_in,
                              void* d_out, int out_size, void* d_ws, size_t ws_size,
                              hipStream_t stream) {
    const float* img    = (const float*)d_in[0];
    const float* heat8  = (const float*)d_in[1];
    const float* heat16 = (const float*)d_in[2];
    const float* heat32 = (const float*)d_in[3];
    const float* seg8   = (const float*)d_in[4];
    const float* seg16  = (const float*)d_in[5];
    const float* seg32  = (const float*)d_in[6];

    float* out     = (float*)d_out;
    float* crops32 = out;                          // (128,1,256,256), g=32, s=8
    float* crops16 = out + (size_t)NB2 * IMG2;     // g=16, s=16
    float* crops8  = out + (size_t)2 * NB2 * IMG2; // g=8,  s=32
    float* label   = out + (size_t)3 * NB2 * IMG2; // (64,1,256,256)

    // crops[32]: s=8  -> 32x32 cells, 64 threads (one wave) per cell
    crops_kernel<8><<<dim3(32 * 32, NB2), 64, 0, stream>>>(img, heat32, crops32);
    // crops[16]: s=16 -> 16x16 cells, 256 threads per cell
    crops_kernel<16><<<dim3(16 * 16, NB2), 256, 0, stream>>>(img, heat16, crops16);
    // crops[8]:  s=32 -> 8x8 cells, 256 threads, 4 px/thread
    crops_kernel<32><<<dim3(8 * 8, NB2), 256, 0, stream>>>(img, heat8, crops8);

    // label: 64 batches x 65536 px, 256 blocks x 256 threads per batch
    label_kernel<<<dim3(IMG2 / 256, NB), 256, 0, stream>>>(
        heat8, heat16, heat32, seg8, seg16, seg32, label);
}

// Round 2
// 229.709 us; speedup vs baseline: 1.3816x; 1.3816x over previous
//
#include <hip/hip_runtime.h>

#define IMG   256
#define IMG2  65536
#define NB    64
#define NB2   128

// ---------------------------------------------------------------------------
// crops kernel v2: one block per (src image, cell-row). Stages the union
// stripe rows [max(ci*S-4,0), ci*S+S) (S+4 rows x 256 cols) into LDS with
// float4 loads, computes per-cell min/max for BOTH the unshifted output
// (batch src) and the shifted output (batch src+64; Y[p] = p<S ? p : p-4),
// then writes both with float4 stores.
// ---------------------------------------------------------------------------
template <int S>
__global__ __launch_bounds__(256) void crops2_kernel(
    const float* __restrict__ img,
    const float* __restrict__ heat,
    float* __restrict__ out) {
    constexpr int G     = IMG / S;
    constexpr int LOG2S = (S == 8) ? 3 : (S == 16) ? 4 : 5;
    constexpr int ROWS  = S + 4;

    __shared__ float tile[ROWS][IMG];
    __shared__ float cAmn[G], cAinv[G], cBmn[G], cBinv[G];

    const int src = blockIdx.y;
    const int ci  = blockIdx.x;
    const int tid = threadIdx.x;

    const int stage_base = (ci == 0) ? 0 : ci * S - 4;
    const float4* img4 = (const float4*)(img + src * IMG2 + stage_base * IMG);

#pragma unroll
    for (int idx = tid; idx < ROWS * 64; idx += 256) {
        const float4 v = img4[idx];
        const int r  = idx >> 6;
        const int c4 = (idx & 63) * 4;
        tile[r][c4 + 0] = v.x;
        tile[r][c4 + 1] = v.y;
        tile[r][c4 + 2] = v.z;
        tile[r][c4 + 3] = v.w;
    }
    __syncthreads();

    // window A (unshifted): LDS rows rA0..rA0+S-1, col = tid
    // window B (shifted):   LDS rows 0..S-1,        col = tid<S ? tid : tid-4
    const int rA0  = (ci == 0) ? 0 : 4;
    const int cj   = tid >> LOG2S;
    const int colB = (tid < S) ? tid : tid - 4;

    float mnA = 3.4e38f, mxA = -3.4e38f, mnB = 3.4e38f, mxB = -3.4e38f;
#pragma unroll
    for (int r = 0; r < S; ++r) {
        const float a = tile[rA0 + r][tid];
        mnA = fminf(mnA, a); mxA = fmaxf(mxA, a);
        const float bv = tile[r][colB];
        mnB = fminf(mnB, bv); mxB = fmaxf(mxB, bv);
    }
#pragma unroll
    for (int off = 1; off < S; off <<= 1) {
        mnA = fminf(mnA, __shfl_xor(mnA, off, 64));
        mxA = fmaxf(mxA, __shfl_xor(mxA, off, 64));
        mnB = fminf(mnB, __shfl_xor(mnB, off, 64));
        mxB = fmaxf(mxB, __shfl_xor(mxB, off, 64));
    }
    if ((tid & (S - 1)) == 0) {
        const float hA = heat[src * G * G + ci * G + cj];
        const float hB = heat[(src + NB) * G * G + ci * G + cj];
        cAmn[cj]  = mnA;
        cAinv[cj] = (hA > 0.5f ? 1.0f : 0.0f) / (mxA - mnA + 1e-5f);
        cBmn[cj]  = mnB;
        cBinv[cj] = (hB > 0.5f ? 1.0f : 0.0f) / (mxB - mnB + 1e-5f);
    }
    __syncthreads();

    float4* outA = (float4*)(out + src * IMG2 + ci * S * IMG);
    float4* outB = (float4*)(out + (src + NB) * IMG2 + ci * S * IMG);
#pragma unroll
    for (int idx = tid; idx < S * 64; idx += 256) {
        const int r  = idx >> 6;
        const int c0 = (idx & 63) * 4;
        const int cc = c0 >> LOG2S;
        {
            const float mn = cAmn[cc], inv = cAinv[cc];
            float4 o;
            o.x = (tile[rA0 + r][c0 + 0] - mn) * inv;
            o.y = (tile[rA0 + r][c0 + 1] - mn) * inv;
            o.z = (tile[rA0 + r][c0 + 2] - mn) * inv;
            o.w = (tile[rA0 + r][c0 + 3] - mn) * inv;
            outA[idx] = o;
        }
        {
            const float mn = cBmn[cc], inv = cBinv[cc];
            const int gb = (c0 < S) ? c0 : c0 - 4;
            float4 o;
            o.x = (tile[r][gb + 0] - mn) * inv;
            o.y = (tile[r][gb + 1] - mn) * inv;
            o.z = (tile[r][gb + 2] - mn) * inv;
            o.w = (tile[r][gb + 3] - mn) * inv;
            outB[idx] = o;
        }
    }
}

// ---------------------------------------------------------------------------
// label kernel v2: one thread per output pixel, u = blockIdx.x (uniform per
// block), v = threadIdx.x. All loads unconditional; contributions gated by
// 0/1 masks via fmaf. Uniform fast path for u in [32,251]: only preimage row
// i = u+4 exists for every scale.
// ---------------------------------------------------------------------------
__global__ __launch_bounds__(256) void label2_kernel(
    const float* __restrict__ heat8,
    const float* __restrict__ heat16,
    const float* __restrict__ heat32,
    const float* __restrict__ seg8,
    const float* __restrict__ seg16,
    const float* __restrict__ seg32,
    float* __restrict__ out) {
    const int b = blockIdx.y;
    const int u = blockIdx.x;
    const int v = threadIdx.x;

    float num = 0.0f, den = 0.0f;

    if (u >= 32 && u <= 251) {
        // fast path: for each scale, direct + gather row i=u+4 only
        const int i1 = u + 4;
        const int j1 = min(v + 4, 255);
#define SCALE_FAST(heat, seg, g, l, s)                                        \
        {                                                                     \
            const float* __restrict__ h1 = heat + b * (g * g);                \
            const float* __restrict__ h2 = heat + (NB + b) * (g * g);         \
            const float* __restrict__ s1 = seg + b * IMG2;                    \
            const float* __restrict__ s2 = seg + (NB + b) * IMG2;             \
            const float hd  = h1[(u >> l) * g + (v >> l)];                    \
            const float sd  = s1[u * IMG + v];                                \
            const float hg0 = h2[(i1 >> l) * g + (v >> l)];                   \
            const float hg1 = h2[(i1 >> l) * g + (j1 >> l)];                  \
            const float sg0 = s2[i1 * IMG + v];                               \
            const float sg1 = s2[i1 * IMG + j1];                              \
            const float md = (hd > 0.5f) ? 1.0f : 0.0f;                       \
            const float m0 = (v < (s) && hg0 > 0.5f) ? 1.0f : 0.0f;           \
            const float m1 = (v >= (s) - 4 && v <= 251 && hg1 > 0.5f)         \
                                 ? 1.0f : 0.0f;                               \
            num = fmaf(md, sd, num);                                          \
            num = fmaf(m0, sg0, num);                                         \
            num = fmaf(m1, sg1, num);                                         \
            den += md + m0 + m1;                                              \
        }
        SCALE_FAST(heat32, seg32, 32, 3, 8)
        SCALE_FAST(heat16, seg16, 16, 4, 16)
        SCALE_FAST(heat8,  seg8,  8,  5, 32)
#undef SCALE_FAST
    } else {
        // generic path: full 2x2 preimage with masks
        const int i0 = u, i1 = min(u + 4, 255);
        const int j0 = v, j1 = min(v + 4, 255);
#define SCALE_GEN(heat, seg, g, l, s)                                         \
        {                                                                     \
            const float* __restrict__ h1 = heat + b * (g * g);                \
            const float* __restrict__ h2 = heat + (NB + b) * (g * g);         \
            const float* __restrict__ s1 = seg + b * IMG2;                    \
            const float* __restrict__ s2 = seg + (NB + b) * IMG2;             \
            const float miA = (u < (s)) ? 1.0f : 0.0f;                        \
            const float miB = (u >= (s) - 4 && u <= 251) ? 1.0f : 0.0f;       \
            const float mjA = (v < (s)) ? 1.0f : 0.0f;                        \
            const float mjB = (v >= (s) - 4 && v <= 251) ? 1.0f : 0.0f;       \
            const float hd  = h1[(u >> l) * g + (v >> l)];                    \
            const float sd  = s1[u * IMG + v];                                \
            const float h00 = h2[(i0 >> l) * g + (j0 >> l)];                  \
            const float h01 = h2[(i0 >> l) * g + (j1 >> l)];                  \
            const float h10 = h2[(i1 >> l) * g + (j0 >> l)];                  \
            const float h11 = h2[(i1 >> l) * g + (j1 >> l)];                  \
            const float s00 = s2[i0 * IMG + j0];                              \
            const float s01 = s2[i0 * IMG + j1];                              \
            const float s10 = s2[i1 * IMG + j0];                              \
            const float s11 = s2[i1 * IMG + j1];                              \
            const float md  = (hd > 0.5f) ? 1.0f : 0.0f;                      \
            const float m00 = (h00 > 0.5f) ? miA * mjA : 0.0f;                \
            const float m01 = (h01 > 0.5f) ? miA * mjB : 0.0f;                \
            const float m10 = (h10 > 0.5f) ? miB * mjA : 0.0f;                \
            const float m11 = (h11 > 0.5f) ? miB * mjB : 0.0f;                \
            num = fmaf(md, sd, num);                                          \
            num = fmaf(m00, s00, num);                                        \
            num = fmaf(m01, s01, num);                                        \
            num = fmaf(m10, s10, num);                                        \
            num = fmaf(m11, s11, num);                                        \
            den += md + m00 + m01 + m10 + m11;                                \
        }
        SCALE_GEN(heat32, seg32, 32, 3, 8)
        SCALE_GEN(heat16, seg16, 16, 4, 16)
        SCALE_GEN(heat8,  seg8,  8,  5, 32)
#undef SCALE_GEN
    }

    out[b * IMG2 + u * IMG + v] = num / (den + 1e-10f);
}

extern "C" void kernel_launch(void* const* d_in, const int* in_sizes, int n_in,
                              void* d_out, int out_size, void* d_ws, size_t ws_size,
                              hipStream_t stream) {
    const float* img    = (const float*)d_in[0];
    const float* heat8  = (const float*)d_in[1];
    const float* heat16 = (const float*)d_in[2];
    const float* heat32 = (const float*)d_in[3];
    const float* seg8   = (const float*)d_in[4];
    const float* seg16  = (const float*)d_in[5];
    const float* seg32  = (const float*)d_in[6];

    float* out     = (float*)d_out;
    float* crops32 = out;                          // (128,1,256,256), s=8
    float* crops16 = out + (size_t)NB2 * IMG2;     // s=16
    float* crops8  = out + (size_t)2 * NB2 * IMG2; // s=32
    float* label   = out + (size_t)3 * NB2 * IMG2; // (64,1,256,256)

    crops2_kernel<8><<<dim3(32, NB), 256, 0, stream>>>(img, heat32, crops32);
    crops2_kernel<16><<<dim3(16, NB), 256, 0, stream>>>(img, heat16, crops16);
    crops2_kernel<32><<<dim3(8, NB), 256, 0, stream>>>(img, heat8, crops8);

    label2_kernel<<<dim3(IMG, NB), 256, 0, stream>>>(
        heat8, heat16, heat32, seg8, seg16, seg32, label);
}